// Round 1
// baseline (3535.035 us; speedup 1.0000x reference)
//
#include <hip/hip_runtime.h>

// EpisodicMemoryModule: B=128, T=512, U=256, EMB=256, 3 memory hops.
// Pipeline per call:
//   prep: facts->bf16, weights transposed->bf16, q/m/memory init
//   once: xr = facts@Wr+br, xh = facts@Wh+bh   (bf16 MFMA GEMM)
//   3x:   scores GEMM (K=1024 fused transforms + tanh + l2 dot) -> softmax
//         -> attention-GRU scan (8 blocks, weights in VGPRs, h in LDS)
//         -> memory update (f32)
//   out = concat(memory, question)

#define DEVI static __device__ __forceinline__

typedef float f32x4 __attribute__((ext_vector_type(4)));
typedef unsigned short u16x8 __attribute__((ext_vector_type(8)));
typedef __bf16 bf16x8 __attribute__((ext_vector_type(8)));

DEVI f32x4 mfma16(u16x8 a, u16x8 b, f32x4 c) {
  return __builtin_amdgcn_mfma_f32_16x16x32_bf16(
      __builtin_bit_cast(bf16x8, a), __builtin_bit_cast(bf16x8, b), c, 0, 0, 0);
}
DEVI float bf2f(unsigned short u) {
  unsigned int x = ((unsigned int)u) << 16;
  return __builtin_bit_cast(float, x);
}
DEVI unsigned short f2bf(float f) {
  unsigned int u = __builtin_bit_cast(unsigned int, f);
  return (unsigned short)((u + 0x7fffu + ((u >> 16) & 1u)) >> 16);
}
DEVI float sigmoid_f(float x) {
  float xc = fminf(fmaxf(x, -30.f), 30.f);
  float e = __expf(-xc);
  return __builtin_amdgcn_rcpf(1.f + e);
}
DEVI float tanh_f(float x) {
  float xc = fminf(fmaxf(x, -15.f), 15.f);
  float e = __expf(-2.f * xc);
  return (1.f - e) * __builtin_amdgcn_rcpf(1.f + e);
}

// ---------------- prep kernels ----------------

__global__ void cast_facts_kernel(const float* __restrict__ in,
                                  unsigned short* __restrict__ out, int n8) {
  int i = blockIdx.x * blockDim.x + threadIdx.x;
  int stride = gridDim.x * blockDim.x;
  for (; i < n8; i += stride) {
    const float4* p = (const float4*)(in + (size_t)i * 8);
    float4 a = p[0], b = p[1];
    u16x8 o;
    o[0] = f2bf(a.x); o[1] = f2bf(a.y); o[2] = f2bf(a.z); o[3] = f2bf(a.w);
    o[4] = f2bf(b.x); o[5] = f2bf(b.y); o[6] = f2bf(b.z); o[7] = f2bf(b.w);
    *(u16x8*)(out + (size_t)i * 8) = o;
  }
}

// z=0..3: transpose+cast Wr,Wh,Ur,Uh (256x256) -> [v][u]
// z=4: l1qT[e][k] (256x512) from l1_W rows {0:256 (W1), 512:768 (W3)}
// z=5: l1mT[e][k] from rows {256:512 (W2), 768:1024 (W4)}
__global__ void prep_weights_kernel(const float* __restrict__ Wr,
                                    const float* __restrict__ Wh,
                                    const float* __restrict__ Ur,
                                    const float* __restrict__ Uh,
                                    const float* __restrict__ l1W,
                                    unsigned short* __restrict__ wrT,
                                    unsigned short* __restrict__ whT,
                                    unsigned short* __restrict__ urT,
                                    unsigned short* __restrict__ uhT,
                                    unsigned short* __restrict__ l1qT,
                                    unsigned short* __restrict__ l1mT) {
  int z = blockIdx.y;
  int r = blockIdx.x;   // 0..255 output row
  int c = threadIdx.x;  // 0..255
  if (z < 4) {
    const float* src = (z == 0) ? Wr : (z == 1) ? Wh : (z == 2) ? Ur : Uh;
    unsigned short* dst = (z == 0) ? wrT : (z == 1) ? whT : (z == 2) ? urT : uhT;
    dst[r * 256 + c] = f2bf(src[c * 256 + r]);
  } else {
    unsigned short* dst = (z == 4) ? l1qT : l1mT;
    for (int kk = c; kk < 512; kk += 256) {
      int srow;
      if (z == 4) srow = (kk < 256) ? kk : (kk + 256);
      else        srow = (kk < 256) ? (kk + 256) : (kk + 512);
      dst[r * 512 + kk] = f2bf(l1W[srow * 256 + r]);
    }
  }
}

__global__ void init_qm_kernel(const float* __restrict__ question,
                               unsigned short* __restrict__ qbf,
                               unsigned short* __restrict__ mbf,
                               float* __restrict__ memory) {
  int i = blockIdx.x * 256 + threadIdx.x;  // 32768
  float v = question[i];
  unsigned short u = f2bf(v);
  qbf[i] = u;
  mbf[i] = u;
  memory[i] = v;
}

// ---------------- GEMM kernels (MFMA 16x16x32 bf16) ----------------
// MODE 0: out[b][t][v] = facts@W + bias; grid (1024, 2): y=0 -> (WT0,bias0,out0)=xr set, y=1 -> xh set. K=256.
// MODE 1: scores[b][t] = sum_e tanh( [f*q|f*m|abs(f-q)|abs(f-m)] @ l1_W + l1_b )[e] * l2_W[e]. K=1024.
template <int MODE>
__global__ __launch_bounds__(256, 2) void gemm_kernel(
    const unsigned short* __restrict__ factsb,
    const unsigned short* __restrict__ WT0,
    const unsigned short* __restrict__ WT1,
    const float* __restrict__ bias0, const float* __restrict__ bias1,
    const unsigned short* __restrict__ vec0,  // q_bf (MODE 1)
    const unsigned short* __restrict__ vec1,  // m_bf (MODE 1)
    unsigned short* __restrict__ out0, unsigned short* __restrict__ out1,
    const float* __restrict__ l2w, float* __restrict__ scores) {
  const int b = blockIdx.x >> 3;
  const int t0 = (blockIdx.x & 7) * 64;
  const int w = threadIdx.x >> 6, l = threadIdx.x & 63;
  const int l15 = l & 15, lg = l >> 4;
  const int koff = lg * 8;
  const int m0 = t0 + w * 16;

  const unsigned short* WT = (MODE == 0 && blockIdx.y == 1) ? WT1 : WT0;
  const float* bias = (MODE == 0 && blockIdx.y == 1) ? bias1 : bias0;
  unsigned short* outp = (MODE == 0 && blockIdx.y == 1) ? out1 : out0;

  u16x8 mvq[8], mvm[8];
  if constexpr (MODE == 1) {
#pragma unroll
    for (int s = 0; s < 8; s++) {
      mvq[s] = *(const u16x8*)&vec0[b * 256 + s * 32 + koff];
      mvm[s] = *(const u16x8*)&vec1[b * 256 + s * 32 + koff];
    }
  }

  f32x4 acc[16];
  const f32x4 zz = {0.f, 0.f, 0.f, 0.f};
#pragma unroll
  for (int nt = 0; nt < 16; nt++) acc[nt] = zz;

  const unsigned short* arow = factsb + ((size_t)b * 512 + (m0 + l15)) * 256;

  if constexpr (MODE == 0) {
#pragma unroll
    for (int ks = 0; ks < 8; ks++) {
      u16x8 a = *(const u16x8*)&arow[ks * 32 + koff];
#pragma unroll
      for (int nt = 0; nt < 16; nt++) {
        u16x8 bb = *(const u16x8*)&WT[(size_t)(nt * 16 + l15) * 256 + ks * 32 + koff];
        acc[nt] = mfma16(a, bb, acc[nt]);
      }
    }
  } else {
    for (int q2 = 0; q2 < 4; q2++) {  // quarter: 0 f*q(W1) 1 f*m(W2) 2 |f-q|(W3) 3 |f-m|(W4)
      const unsigned short* WTs = (q2 & 1) ? WT1 : WT0;
      const int bko = (q2 >> 1) * 256;
      const bool isabs = (q2 >= 2);
#pragma unroll
      for (int kss = 0; kss < 8; kss++) {
        u16x8 f = *(const u16x8*)&arow[kss * 32 + koff];
        u16x8 vv = (q2 & 1) ? mvm[kss] : mvq[kss];
        u16x8 a;
#pragma unroll
        for (int j = 0; j < 8; j++) {
          float fv = bf2f(f[j]), qv = bf2f(vv[j]);
          float rr = isabs ? fabsf(fv - qv) : fv * qv;
          a[j] = f2bf(rr);
        }
#pragma unroll
        for (int nt = 0; nt < 16; nt++) {
          u16x8 bb = *(const u16x8*)&WTs[(size_t)(nt * 16 + l15) * 512 + bko + kss * 32 + koff];
          acc[nt] = mfma16(a, bb, acc[nt]);
        }
      }
    }
  }

  if constexpr (MODE == 0) {
#pragma unroll
    for (int nt = 0; nt < 16; nt++) {
      const int col = nt * 16 + l15;
      const float bv = bias[col];
#pragma unroll
      for (int r = 0; r < 4; r++) {
        const int t = m0 + lg * 4 + r;
        outp[((size_t)b * 512 + t) * 256 + col] = f2bf(acc[nt][r] + bv);
      }
    }
  } else {
    float part[4] = {0.f, 0.f, 0.f, 0.f};
#pragma unroll
    for (int nt = 0; nt < 16; nt++) {
      const int col = nt * 16 + l15;
      const float lw = l2w[col];
      const float bv = bias[col];  // l1_b
#pragma unroll
      for (int r = 0; r < 4; r++) part[r] += tanh_f(acc[nt][r] + bv) * lw;
    }
#pragma unroll
    for (int m = 1; m < 16; m <<= 1) {
#pragma unroll
      for (int r = 0; r < 4; r++) part[r] += __shfl_xor(part[r], m, 64);
    }
    if (l15 == 0) {
#pragma unroll
      for (int r = 0; r < 4; r++)
        scores[(size_t)b * 512 + m0 + lg * 4 + r] = part[r];  // l2_b dropped: softmax-invariant
    }
  }
}

// ---------------- softmax over T per batch ----------------
__global__ void softmax_kernel(const float* __restrict__ scores,
                               float* __restrict__ att) {
  int b = blockIdx.x;
  int l = threadIdx.x;  // 64 threads, 8 scores each
  float v[8];
#pragma unroll
  for (int i = 0; i < 8; i++) v[i] = scores[b * 512 + l * 8 + i];
  float mx = v[0];
#pragma unroll
  for (int i = 1; i < 8; i++) mx = fmaxf(mx, v[i]);
#pragma unroll
  for (int m = 1; m < 64; m <<= 1) mx = fmaxf(mx, __shfl_xor(mx, m, 64));
  float s = 0.f;
#pragma unroll
  for (int i = 0; i < 8; i++) { v[i] = __expf(v[i] - mx); s += v[i]; }
#pragma unroll
  for (int m = 1; m < 64; m <<= 1) s += __shfl_xor(s, m, 64);
  float inv = __builtin_amdgcn_rcpf(s);
#pragma unroll
  for (int i = 0; i < 8; i++) att[(l * 8 + i) * 128 + b] = v[i] * inv;
}

// ---------------- attention-GRU scan ----------------
// 8 blocks x 512 threads (8 waves). Block = 16 batches. Wave w owns cols [w*32, w*32+32).
// Ur/Uh B-fragments fully preloaded in VGPRs. h lives in LDS (bf16, padded stride).
__global__ __launch_bounds__(512, 2) void scan_kernel(
    const unsigned short* __restrict__ xrb,  // [B][T][U] bf16
    const unsigned short* __restrict__ xhb,
    const float* __restrict__ att,           // [T][B]
    const unsigned short* __restrict__ urT,  // [v][u] bf16
    const unsigned short* __restrict__ uhT,
    float* __restrict__ episode)             // [B][U] f32
{
  constexpr int PAD = 264;  // 256 + 8 -> 528B row stride, conflict-free b128 reads
  __shared__ unsigned short hlds[16 * PAD];
  __shared__ unsigned short rhlds[16 * PAD];
  const int w = threadIdx.x >> 6, l = threadIdx.x & 63;
  const int l15 = l & 15, lg = l >> 4;
  const int koff = lg * 8;
  const int c0 = w * 32;
  const int b0 = blockIdx.x * 16;
  const int lb = lg * 4;

  u16x8 urf0[8], urf1[8], uhf0[8], uhf1[8];
#pragma unroll
  for (int ks = 0; ks < 8; ks++) {
    const int colA = c0 + l15, colB = c0 + 16 + l15;
    urf0[ks] = *(const u16x8*)&urT[colA * 256 + ks * 32 + koff];
    urf1[ks] = *(const u16x8*)&urT[colB * 256 + ks * 32 + koff];
    uhf0[ks] = *(const u16x8*)&uhT[colA * 256 + ks * 32 + koff];
    uhf1[ks] = *(const u16x8*)&uhT[colB * 256 + ks * 32 + koff];
  }
  for (int i = threadIdx.x; i < 16 * PAD; i += 512) { hlds[i] = 0; rhlds[i] = 0; }
  __syncthreads();

  float hc0[4], hc1[4];
#pragma unroll
  for (int r = 0; r < 4; r++) { hc0[r] = 0.f; hc1[r] = 0.f; }
  const f32x4 zz = {0.f, 0.f, 0.f, 0.f};

  for (int t = 0; t < 512; t++) {
    // issue this step's xr/xh/att loads early; consumed after MFMA1
    unsigned short xr0[4], xr1[4], xh0[4], xh1[4];
    float gv[4];
#pragma unroll
    for (int r = 0; r < 4; r++) {
      const size_t base = ((size_t)(b0 + lb + r) * 512 + t) * 256;
      xr0[r] = xrb[base + c0 + l15];
      xr1[r] = xrb[base + c0 + 16 + l15];
      xh0[r] = xhb[base + c0 + l15];
      xh1[r] = xhb[base + c0 + 16 + l15];
      gv[r] = att[t * 128 + b0 + lb + r];
    }

    u16x8 hf[8];
#pragma unroll
    for (int ks = 0; ks < 8; ks++)
      hf[ks] = *(const u16x8*)&hlds[l15 * PAD + ks * 32 + koff];

    f32x4 acc0 = zz, acc1 = zz;
#pragma unroll
    for (int ks = 0; ks < 8; ks++) {
      acc0 = mfma16(hf[ks], urf0[ks], acc0);
      acc1 = mfma16(hf[ks], urf1[ks], acc1);
    }
#pragma unroll
    for (int r = 0; r < 4; r++) {
      float rg0 = sigmoid_f(acc0[r] + bf2f(xr0[r]));
      float rg1 = sigmoid_f(acc1[r] + bf2f(xr1[r]));
      rhlds[(lb + r) * PAD + c0 + l15] = f2bf(rg0 * hc0[r]);
      rhlds[(lb + r) * PAD + c0 + 16 + l15] = f2bf(rg1 * hc1[r]);
    }
    __syncthreads();

    u16x8 rf[8];
#pragma unroll
    for (int ks = 0; ks < 8; ks++)
      rf[ks] = *(const u16x8*)&rhlds[l15 * PAD + ks * 32 + koff];

    f32x4 a20 = zz, a21 = zz;
#pragma unroll
    for (int ks = 0; ks < 8; ks++) {
      a20 = mfma16(rf[ks], uhf0[ks], a20);
      a21 = mfma16(rf[ks], uhf1[ks], a21);
    }
#pragma unroll
    for (int r = 0; r < 4; r++) {
      float ht0 = tanh_f(a20[r] + bf2f(xh0[r]));
      float ht1 = tanh_f(a21[r] + bf2f(xh1[r]));
      float hn0 = hc0[r] + gv[r] * (ht0 - hc0[r]);
      float hn1 = hc1[r] + gv[r] * (ht1 - hc1[r]);
      hc0[r] = hn0; hc1[r] = hn1;
      hlds[(lb + r) * PAD + c0 + l15] = f2bf(hn0);
      hlds[(lb + r) * PAD + c0 + 16 + l15] = f2bf(hn1);
    }
    __syncthreads();
  }
#pragma unroll
  for (int r = 0; r < 4; r++) {
    episode[(size_t)(b0 + lb + r) * 256 + c0 + l15] = hc0[r];
    episode[(size_t)(b0 + lb + r) * 256 + c0 + 16 + l15] = hc1[r];
  }
}

// ---------------- memory update ----------------
__global__ __launch_bounds__(256) void memupd_kernel(
    const float* __restrict__ episode, const float* __restrict__ question,
    const float* __restrict__ memW, const float* __restrict__ memb,
    float* __restrict__ memory, unsigned short* __restrict__ mbf) {
  __shared__ float cat[768];
  int b = blockIdx.x, v = threadIdx.x;
  cat[v] = memory[b * 256 + v];
  cat[256 + v] = episode[b * 256 + v];
  cat[512 + v] = question[b * 256 + v];
  __syncthreads();
  float acc = memb[v];
#pragma unroll 8
  for (int u = 0; u < 768; u++) acc += cat[u] * memW[u * 256 + v];
  acc = fmaxf(acc, 0.f);
  memory[b * 256 + v] = acc;
  mbf[b * 256 + v] = f2bf(acc);
}

__global__ void writeout_kernel(const float* __restrict__ memory,
                                const float* __restrict__ question,
                                float* __restrict__ out) {
  int i = blockIdx.x * 256 + threadIdx.x;  // 65536
  int b = i >> 9, c = i & 511;
  out[i] = (c < 256) ? memory[b * 256 + c] : question[b * 256 + (c - 256)];
}

// ---------------- launch ----------------
extern "C" void kernel_launch(void* const* d_in, const int* in_sizes, int n_in,
                              void* d_out, int out_size, void* d_ws, size_t ws_size,
                              hipStream_t stream) {
  (void)in_sizes; (void)n_in; (void)out_size; (void)ws_size;
  const float* facts = (const float*)d_in[0];
  const float* question = (const float*)d_in[1];
  const float* l1W = (const float*)d_in[2];
  const float* l1b = (const float*)d_in[3];
  const float* l2W = (const float*)d_in[4];
  const float* Wr = (const float*)d_in[6];
  const float* Ur = (const float*)d_in[7];
  const float* br = (const float*)d_in[8];
  const float* Wh = (const float*)d_in[9];
  const float* Uh = (const float*)d_in[10];
  const float* bh = (const float*)d_in[11];
  const float* memW = (const float*)d_in[12];
  const float* memb = (const float*)d_in[13];
  float* out = (float*)d_out;

  char* ws = (char*)d_ws;  // total required: ~98.4 MB
  unsigned short* factsb = (unsigned short*)(ws + 0);          // 33,554,432 B
  unsigned short* xrb    = (unsigned short*)(ws + 33554432);   // 33,554,432 B
  unsigned short* xhb    = (unsigned short*)(ws + 67108864);   // 33,554,432 B
  unsigned short* wrT    = (unsigned short*)(ws + 100663296);  // 131,072 B
  unsigned short* whT    = (unsigned short*)(ws + 100794368);
  unsigned short* urT    = (unsigned short*)(ws + 100925440);
  unsigned short* uhT    = (unsigned short*)(ws + 101056512);
  unsigned short* l1qT   = (unsigned short*)(ws + 101187584);  // 524,288 B
  unsigned short* l1mT   = (unsigned short*)(ws + 101711872);  // 524,288 B
  unsigned short* qbf    = (unsigned short*)(ws + 102236160);  // 65,536 B
  unsigned short* mbf    = (unsigned short*)(ws + 102301696);  // 65,536 B
  float* scores          = (float*)(ws + 102367232);           // 262,144 B
  float* att             = (float*)(ws + 102629376);           // 262,144 B
  float* memory          = (float*)(ws + 102891520);           // 131,072 B
  float* episode         = (float*)(ws + 103022592);           // 131,072 B

  cast_facts_kernel<<<2048, 256, 0, stream>>>(facts, factsb, 2097152);
  prep_weights_kernel<<<dim3(256, 6), 256, 0, stream>>>(Wr, Wh, Ur, Uh, l1W,
                                                        wrT, whT, urT, uhT, l1qT, l1mT);
  init_qm_kernel<<<128, 256, 0, stream>>>(question, qbf, mbf, memory);

  // xr / xh (memory-independent, computed once)
  gemm_kernel<0><<<dim3(1024, 2), 256, 0, stream>>>(
      factsb, wrT, whT, br, bh, nullptr, nullptr, xrb, xhb, nullptr, nullptr);

  for (int step = 0; step < 3; step++) {
    gemm_kernel<1><<<dim3(1024, 1), 256, 0, stream>>>(
        factsb, l1qT, l1mT, l1b, nullptr, qbf, mbf, nullptr, nullptr, l2W, scores);
    softmax_kernel<<<128, 64, 0, stream>>>(scores, att);
    scan_kernel<<<8, 512, 0, stream>>>(xrb, xhb, att, urT, uhT, episode);
    memupd_kernel<<<128, 256, 0, stream>>>(episode, question, memW, memb, memory, mbf);
  }
  writeout_kernel<<<256, 256, 0, stream>>>(memory, question, out);
}

// Round 2
// 3036.809 us; speedup vs baseline: 1.1641x; 1.1641x over previous
//
#include <hip/hip_runtime.h>

// EpisodicMemoryModule: B=128, T=512, U=256, EMB=256, 3 memory hops.
// Round 2: scan restructured — xr/xh interleaved [T][B][2U] bf16 with 1-step
// register prefetch, cvt_pk_bf16 packing, clamp-free sigmoid, split MFMA chains.

#define DEVI static __device__ __forceinline__

typedef float f32x4 __attribute__((ext_vector_type(4)));
typedef unsigned short u16x8 __attribute__((ext_vector_type(8)));
typedef __bf16 bf16x8 __attribute__((ext_vector_type(8)));

DEVI f32x4 mfma16(u16x8 a, u16x8 b, f32x4 c) {
  return __builtin_amdgcn_mfma_f32_16x16x32_bf16(
      __builtin_bit_cast(bf16x8, a), __builtin_bit_cast(bf16x8, b), c, 0, 0, 0);
}
DEVI float bf2f(unsigned short u) {
  unsigned int x = ((unsigned int)u) << 16;
  return __builtin_bit_cast(float, x);
}
DEVI float lo2f(unsigned int u) {  // low bf16 of packed pair -> f32
  unsigned int x = u << 16;
  return __builtin_bit_cast(float, x);
}
DEVI float hi2f(unsigned int u) {  // high bf16 of packed pair -> f32
  unsigned int x = u & 0xffff0000u;
  return __builtin_bit_cast(float, x);
}
DEVI unsigned short f2bf(float f) {
  unsigned int u = __builtin_bit_cast(unsigned int, f);
  return (unsigned short)((u + 0x7fffu + ((u >> 16) & 1u)) >> 16);
}
DEVI unsigned int cvtpk(float lo, float hi) {  // RTNE pack: [bf16(lo) | bf16(hi)<<16]
  unsigned int r;
  asm("v_cvt_pk_bf16_f32 %0, %1, %2" : "=v"(r) : "v"(lo), "v"(hi));
  return r;
}
DEVI float sigmoid_f(float x) {  // inf-safe without clamps: rcp(inf)=0
  float e = __expf(-x);
  return __builtin_amdgcn_rcpf(1.f + e);
}
DEVI float tanh_f(float x) {  // one-sided clamp avoids (1-inf)*0 = NaN
  float xc = fmaxf(x, -12.f);
  float e = __expf(-2.f * xc);
  return (1.f - e) * __builtin_amdgcn_rcpf(1.f + e);
}

// ---------------- prep kernels ----------------

__global__ void cast_facts_kernel(const float* __restrict__ in,
                                  unsigned short* __restrict__ out, int n8) {
  int i = blockIdx.x * blockDim.x + threadIdx.x;
  int stride = gridDim.x * blockDim.x;
  for (; i < n8; i += stride) {
    const float4* p = (const float4*)(in + (size_t)i * 8);
    float4 a = p[0], b = p[1];
    u16x8 o;
    o[0] = f2bf(a.x); o[1] = f2bf(a.y); o[2] = f2bf(a.z); o[3] = f2bf(a.w);
    o[4] = f2bf(b.x); o[5] = f2bf(b.y); o[6] = f2bf(b.z); o[7] = f2bf(b.w);
    *(u16x8*)(out + (size_t)i * 8) = o;
  }
}

// z=0..3: transpose+cast Wr,Wh,Ur,Uh (256x256) -> [v][u]
// z=4: l1qT[e][k] (256x512) from l1_W rows {0:256 (W1), 512:768 (W3)}
// z=5: l1mT[e][k] from rows {256:512 (W2), 768:1024 (W4)}
__global__ void prep_weights_kernel(const float* __restrict__ Wr,
                                    const float* __restrict__ Wh,
                                    const float* __restrict__ Ur,
                                    const float* __restrict__ Uh,
                                    const float* __restrict__ l1W,
                                    unsigned short* __restrict__ wrT,
                                    unsigned short* __restrict__ whT,
                                    unsigned short* __restrict__ urT,
                                    unsigned short* __restrict__ uhT,
                                    unsigned short* __restrict__ l1qT,
                                    unsigned short* __restrict__ l1mT) {
  int z = blockIdx.y;
  int r = blockIdx.x;   // 0..255 output row
  int c = threadIdx.x;  // 0..255
  if (z < 4) {
    const float* src = (z == 0) ? Wr : (z == 1) ? Wh : (z == 2) ? Ur : Uh;
    unsigned short* dst = (z == 0) ? wrT : (z == 1) ? whT : (z == 2) ? urT : uhT;
    dst[r * 256 + c] = f2bf(src[c * 256 + r]);
  } else {
    unsigned short* dst = (z == 4) ? l1qT : l1mT;
    for (int kk = c; kk < 512; kk += 256) {
      int srow;
      if (z == 4) srow = (kk < 256) ? kk : (kk + 256);
      else        srow = (kk < 256) ? (kk + 256) : (kk + 512);
      dst[r * 512 + kk] = f2bf(l1W[srow * 256 + r]);
    }
  }
}

__global__ void init_qm_kernel(const float* __restrict__ question,
                               unsigned short* __restrict__ qbf,
                               unsigned short* __restrict__ mbf,
                               float* __restrict__ memory) {
  int i = blockIdx.x * 256 + threadIdx.x;  // 32768
  float v = question[i];
  unsigned short u = f2bf(v);
  qbf[i] = u;
  mbf[i] = u;
  memory[i] = v;
}

// ---------------- xr/xh GEMM (fused, writes interleaved [T][B][2U]) ----------------
// xrxh[t][b][2*col+0] = bf16(facts@Wr + br), [2*col+1] = bf16(facts@Wh + bh)
__global__ __launch_bounds__(256, 2) void gemm_xrxh_kernel(
    const unsigned short* __restrict__ factsb,
    const unsigned short* __restrict__ wrT,
    const unsigned short* __restrict__ whT,
    const float* __restrict__ br, const float* __restrict__ bh,
    unsigned short* __restrict__ xrxh) {
  const int b = blockIdx.x >> 3;
  const int t0 = (blockIdx.x & 7) * 64;
  const int w = threadIdx.x >> 6, l = threadIdx.x & 63;
  const int l15 = l & 15, lg = l >> 4;
  const int koff = lg * 8;
  const int m0 = t0 + w * 16;

  f32x4 accR[16], accH[16];
  const f32x4 zz = {0.f, 0.f, 0.f, 0.f};
#pragma unroll
  for (int nt = 0; nt < 16; nt++) { accR[nt] = zz; accH[nt] = zz; }

  const unsigned short* arow = factsb + ((size_t)b * 512 + (m0 + l15)) * 256;
#pragma unroll
  for (int ks = 0; ks < 8; ks++) {
    u16x8 a = *(const u16x8*)&arow[ks * 32 + koff];
#pragma unroll
    for (int nt = 0; nt < 16; nt++) {
      u16x8 bwr = *(const u16x8*)&wrT[(size_t)(nt * 16 + l15) * 256 + ks * 32 + koff];
      u16x8 bwh = *(const u16x8*)&whT[(size_t)(nt * 16 + l15) * 256 + ks * 32 + koff];
      accR[nt] = mfma16(a, bwr, accR[nt]);
      accH[nt] = mfma16(a, bwh, accH[nt]);
    }
  }
#pragma unroll
  for (int nt = 0; nt < 16; nt++) {
    const int col = nt * 16 + l15;
    const float bvr = br[col], bvh = bh[col];
#pragma unroll
    for (int r = 0; r < 4; r++) {
      const int t = m0 + lg * 4 + r;
      unsigned int pk = cvtpk(accR[nt][r] + bvr, accH[nt][r] + bvh);
      *(unsigned int*)&xrxh[((size_t)t * 128 + b) * 512 + col * 2] = pk;
    }
  }
}

// ---------------- attention scores GEMM (K=1024 fused transforms) ----------------
__global__ __launch_bounds__(256, 2) void scores_kernel(
    const unsigned short* __restrict__ factsb,
    const unsigned short* __restrict__ l1qT,
    const unsigned short* __restrict__ l1mT,
    const float* __restrict__ l1b,
    const unsigned short* __restrict__ qbf,
    const unsigned short* __restrict__ mbf,
    const float* __restrict__ l2w, float* __restrict__ scores) {
  const int b = blockIdx.x >> 3;
  const int t0 = (blockIdx.x & 7) * 64;
  const int w = threadIdx.x >> 6, l = threadIdx.x & 63;
  const int l15 = l & 15, lg = l >> 4;
  const int koff = lg * 8;
  const int m0 = t0 + w * 16;

  u16x8 mvq[8], mvm[8];
#pragma unroll
  for (int s = 0; s < 8; s++) {
    mvq[s] = *(const u16x8*)&qbf[b * 256 + s * 32 + koff];
    mvm[s] = *(const u16x8*)&mbf[b * 256 + s * 32 + koff];
  }

  f32x4 acc[16];
  const f32x4 zz = {0.f, 0.f, 0.f, 0.f};
#pragma unroll
  for (int nt = 0; nt < 16; nt++) acc[nt] = zz;

  const unsigned short* arow = factsb + ((size_t)b * 512 + (m0 + l15)) * 256;

  for (int q2 = 0; q2 < 4; q2++) {  // 0 f*q(W1) 1 f*m(W2) 2 |f-q|(W3) 3 |f-m|(W4)
    const unsigned short* WTs = (q2 & 1) ? l1mT : l1qT;
    const int bko = (q2 >> 1) * 256;
    const bool isabs = (q2 >= 2);
#pragma unroll
    for (int kss = 0; kss < 8; kss++) {
      u16x8 f = *(const u16x8*)&arow[kss * 32 + koff];
      u16x8 vv = (q2 & 1) ? mvm[kss] : mvq[kss];
      u16x8 a;
#pragma unroll
      for (int j = 0; j < 8; j++) {
        float fv = bf2f(f[j]), qv = bf2f(vv[j]);
        float rr = isabs ? fabsf(fv - qv) : fv * qv;
        a[j] = f2bf(rr);
      }
#pragma unroll
      for (int nt = 0; nt < 16; nt++) {
        u16x8 bb = *(const u16x8*)&WTs[(size_t)(nt * 16 + l15) * 512 + bko + kss * 32 + koff];
        acc[nt] = mfma16(a, bb, acc[nt]);
      }
    }
  }

  float part[4] = {0.f, 0.f, 0.f, 0.f};
#pragma unroll
  for (int nt = 0; nt < 16; nt++) {
    const int col = nt * 16 + l15;
    const float lw = l2w[col];
    const float bv = l1b[col];
#pragma unroll
    for (int r = 0; r < 4; r++) part[r] += tanh_f(acc[nt][r] + bv) * lw;
  }
#pragma unroll
  for (int m = 1; m < 16; m <<= 1) {
#pragma unroll
    for (int r = 0; r < 4; r++) part[r] += __shfl_xor(part[r], m, 64);
  }
  if (l15 == 0) {
#pragma unroll
    for (int r = 0; r < 4; r++)
      scores[(size_t)b * 512 + m0 + lg * 4 + r] = part[r];  // l2_b: softmax-invariant
  }
}

// ---------------- softmax over T per batch ----------------
__global__ void softmax_kernel(const float* __restrict__ scores,
                               float* __restrict__ att) {
  int b = blockIdx.x;
  int l = threadIdx.x;  // 64 threads, 8 scores each
  float v[8];
#pragma unroll
  for (int i = 0; i < 8; i++) v[i] = scores[b * 512 + l * 8 + i];
  float mx = v[0];
#pragma unroll
  for (int i = 1; i < 8; i++) mx = fmaxf(mx, v[i]);
#pragma unroll
  for (int m = 1; m < 64; m <<= 1) mx = fmaxf(mx, __shfl_xor(mx, m, 64));
  float s = 0.f;
#pragma unroll
  for (int i = 0; i < 8; i++) { v[i] = __expf(v[i] - mx); s += v[i]; }
#pragma unroll
  for (int m = 1; m < 64; m <<= 1) s += __shfl_xor(s, m, 64);
  float inv = __builtin_amdgcn_rcpf(s);
#pragma unroll
  for (int i = 0; i < 8; i++) att[(l * 8 + i) * 128 + b] = v[i] * inv;
}

// ---------------- attention-GRU scan ----------------
// 8 blocks x 512 threads (8 waves). Block = 16 batches, wave w owns cols [32w,32w+32).
// Per-step: A-frag from LDS -> 4+4 split MFMA chains -> sigmoid -> LDS exchange
// -> 4+4 MFMA -> tanh/blend -> LDS write. xr/xh/att prefetched one step ahead.
struct PF {
  unsigned int x0[4], x1[4];  // packed (xr,xh) bf16 pairs
  f32x4 g;
};

__global__ __launch_bounds__(512, 2) void scan_kernel(
    const unsigned short* __restrict__ xrxh,  // [T][B][2U] bf16 interleaved
    const float* __restrict__ att,            // [T][B]
    const unsigned short* __restrict__ urT,   // [v][u] bf16
    const unsigned short* __restrict__ uhT,
    float* __restrict__ episode)              // [B][U] f32
{
  constexpr int PAD = 264;  // 528B row stride: 2-way floor for b128 (free per m136)
  __shared__ unsigned short hlds[16 * PAD];
  __shared__ unsigned short rhlds[16 * PAD];
  const int w = threadIdx.x >> 6, l = threadIdx.x & 63;
  const int l15 = l & 15, lg = l >> 4;
  const int koff = lg * 8;
  const int c0 = w * 32;
  const int b0 = blockIdx.x * 16;
  const int lb = lg * 4;

  u16x8 urf0[8], urf1[8], uhf0[8], uhf1[8];
#pragma unroll
  for (int ks = 0; ks < 8; ks++) {
    const int colA = c0 + l15, colB = c0 + 16 + l15;
    urf0[ks] = *(const u16x8*)&urT[colA * 256 + ks * 32 + koff];
    urf1[ks] = *(const u16x8*)&urT[colB * 256 + ks * 32 + koff];
    uhf0[ks] = *(const u16x8*)&uhT[colA * 256 + ks * 32 + koff];
    uhf1[ks] = *(const u16x8*)&uhT[colB * 256 + ks * 32 + koff];
  }
  for (int i = threadIdx.x; i < 16 * PAD; i += 512) hlds[i] = 0;
  __syncthreads();

  // hoisted per-thread constant addresses
  const int hread = l15 * PAD + koff;
  int wa0[4], wa1[4], ro0[4], ro1[4];
#pragma unroll
  for (int r = 0; r < 4; r++) {
    wa0[r] = (lb + r) * PAD + c0 + l15;
    wa1[r] = wa0[r] + 16;
    ro0[r] = (b0 + lb + r) * 512 + (c0 + l15) * 2;
    ro1[r] = ro0[r] + 32;
  }
  const int attoff = b0 + lb;

  float hc0[4] = {0.f, 0.f, 0.f, 0.f}, hc1[4] = {0.f, 0.f, 0.f, 0.f};
  const f32x4 zz = {0.f, 0.f, 0.f, 0.f};

  auto prefetch = [&](int t) {
    PF p;
    const unsigned short* xb = xrxh + (size_t)t * 65536;  // uniform base -> SGPR
#pragma unroll
    for (int r = 0; r < 4; r++) {
      p.x0[r] = *(const unsigned int*)&xb[ro0[r]];
      p.x1[r] = *(const unsigned int*)&xb[ro1[r]];
    }
    p.g = *(const f32x4*)&att[t * 128 + attoff];
    return p;
  };

  auto step = [&](const PF& pf) {
    u16x8 hf[8];
#pragma unroll
    for (int ks = 0; ks < 8; ks++)
      hf[ks] = *(const u16x8*)&hlds[hread + ks * 32];
    f32x4 a0a = zz, a0b = zz, a1a = zz, a1b = zz;
#pragma unroll
    for (int ks = 0; ks < 4; ks++) {
      a0a = mfma16(hf[ks], urf0[ks], a0a);
      a1a = mfma16(hf[ks], urf1[ks], a1a);
      a0b = mfma16(hf[ks + 4], urf0[ks + 4], a0b);
      a1b = mfma16(hf[ks + 4], urf1[ks + 4], a1b);
    }
    f32x4 accR0 = a0a + a0b, accR1 = a1a + a1b;
#pragma unroll
    for (int r = 0; r < 4; r++) {
      float rg0 = sigmoid_f(accR0[r] + lo2f(pf.x0[r]));
      float rg1 = sigmoid_f(accR1[r] + lo2f(pf.x1[r]));
      unsigned int pk = cvtpk(rg0 * hc0[r], rg1 * hc1[r]);
      rhlds[wa0[r]] = (unsigned short)pk;
      rhlds[wa1[r]] = (unsigned short)(pk >> 16);
    }
    __syncthreads();
    u16x8 rf[8];
#pragma unroll
    for (int ks = 0; ks < 8; ks++)
      rf[ks] = *(const u16x8*)&rhlds[hread + ks * 32];
    f32x4 b0a = zz, b0b = zz, b1a = zz, b1b = zz;
#pragma unroll
    for (int ks = 0; ks < 4; ks++) {
      b0a = mfma16(rf[ks], uhf0[ks], b0a);
      b1a = mfma16(rf[ks], uhf1[ks], b1a);
      b0b = mfma16(rf[ks + 4], uhf0[ks + 4], b0b);
      b1b = mfma16(rf[ks + 4], uhf1[ks + 4], b1b);
    }
    f32x4 accH0 = b0a + b0b, accH1 = b1a + b1b;
#pragma unroll
    for (int r = 0; r < 4; r++) {
      float ht0 = tanh_f(accH0[r] + hi2f(pf.x0[r]));
      float ht1 = tanh_f(accH1[r] + hi2f(pf.x1[r]));
      float g = pf.g[r];
      hc0[r] = fmaf(g, ht0 - hc0[r], hc0[r]);
      hc1[r] = fmaf(g, ht1 - hc1[r], hc1[r]);
      unsigned int pk = cvtpk(hc0[r], hc1[r]);
      hlds[wa0[r]] = (unsigned short)pk;
      hlds[wa1[r]] = (unsigned short)(pk >> 16);
    }
    __syncthreads();
  };

  PF cur = prefetch(0);
#pragma unroll 2
  for (int t = 0; t < 512; t++) {
    PF nxt = prefetch(t + 1);  // t=511 prefetch reads adjacent ws (unused, safe)
    step(cur);
    cur = nxt;
  }
#pragma unroll
  for (int r = 0; r < 4; r++) {
    episode[(size_t)(b0 + lb + r) * 256 + c0 + l15] = hc0[r];
    episode[(size_t)(b0 + lb + r) * 256 + c0 + 16 + l15] = hc1[r];
  }
}

// ---------------- memory update ----------------
__global__ __launch_bounds__(256) void memupd_kernel(
    const float* __restrict__ episode, const float* __restrict__ question,
    const float* __restrict__ memW, const float* __restrict__ memb,
    float* __restrict__ memory, unsigned short* __restrict__ mbf) {
  __shared__ float cat[768];
  int b = blockIdx.x, v = threadIdx.x;
  cat[v] = memory[b * 256 + v];
  cat[256 + v] = episode[b * 256 + v];
  cat[512 + v] = question[b * 256 + v];
  __syncthreads();
  float acc = memb[v];
#pragma unroll 8
  for (int u = 0; u < 768; u++) acc += cat[u] * memW[u * 256 + v];
  acc = fmaxf(acc, 0.f);
  memory[b * 256 + v] = acc;
  mbf[b * 256 + v] = f2bf(acc);
}

__global__ void writeout_kernel(const float* __restrict__ memory,
                                const float* __restrict__ question,
                                float* __restrict__ out) {
  int i = blockIdx.x * 256 + threadIdx.x;  // 65536
  int b = i >> 9, c = i & 511;
  out[i] = (c < 256) ? memory[b * 256 + c] : question[b * 256 + (c - 256)];
}

// ---------------- launch ----------------
extern "C" void kernel_launch(void* const* d_in, const int* in_sizes, int n_in,
                              void* d_out, int out_size, void* d_ws, size_t ws_size,
                              hipStream_t stream) {
  (void)in_sizes; (void)n_in; (void)out_size; (void)ws_size;
  const float* facts = (const float*)d_in[0];
  const float* question = (const float*)d_in[1];
  const float* l1W = (const float*)d_in[2];
  const float* l1b = (const float*)d_in[3];
  const float* l2W = (const float*)d_in[4];
  const float* Wr = (const float*)d_in[6];
  const float* Ur = (const float*)d_in[7];
  const float* br = (const float*)d_in[8];
  const float* Wh = (const float*)d_in[9];
  const float* Uh = (const float*)d_in[10];
  const float* bh = (const float*)d_in[11];
  const float* memW = (const float*)d_in[12];
  const float* memb = (const float*)d_in[13];
  float* out = (float*)d_out;

  char* ws = (char*)d_ws;  // total ~98.4 MB (same footprint as validated round 1)
  unsigned short* factsb = (unsigned short*)(ws + 0);          // 33,554,432 B
  unsigned short* xrxh   = (unsigned short*)(ws + 33554432);   // 67,108,864 B [T][B][2U]
  unsigned short* wrT    = (unsigned short*)(ws + 100663296);  // 131,072 B
  unsigned short* whT    = (unsigned short*)(ws + 100794368);
  unsigned short* urT    = (unsigned short*)(ws + 100925440);
  unsigned short* uhT    = (unsigned short*)(ws + 101056512);
  unsigned short* l1qT   = (unsigned short*)(ws + 101187584);  // 524,288 B
  unsigned short* l1mT   = (unsigned short*)(ws + 101711872);  // 524,288 B
  unsigned short* qbf    = (unsigned short*)(ws + 102236160);  // 65,536 B
  unsigned short* mbf    = (unsigned short*)(ws + 102301696);  // 65,536 B
  float* scores          = (float*)(ws + 102367232);           // 262,144 B
  float* att             = (float*)(ws + 102629376);           // 262,144 B
  float* memory          = (float*)(ws + 102891520);           // 131,072 B
  float* episode         = (float*)(ws + 103022592);           // 131,072 B

  cast_facts_kernel<<<2048, 256, 0, stream>>>(facts, factsb, 2097152);
  prep_weights_kernel<<<dim3(256, 6), 256, 0, stream>>>(Wr, Wh, Ur, Uh, l1W,
                                                        wrT, whT, urT, uhT, l1qT, l1mT);
  init_qm_kernel<<<128, 256, 0, stream>>>(question, qbf, mbf, memory);

  gemm_xrxh_kernel<<<1024, 256, 0, stream>>>(factsb, wrT, whT, br, bh, xrxh);

  for (int step = 0; step < 3; step++) {
    scores_kernel<<<1024, 256, 0, stream>>>(factsb, l1qT, l1mT, l1b, qbf, mbf, l2W, scores);
    softmax_kernel<<<128, 64, 0, stream>>>(scores, att);
    scan_kernel<<<8, 512, 0, stream>>>(xrxh, att, urT, uhT, episode);
    memupd_kernel<<<128, 256, 0, stream>>>(episode, question, memW, memb, memory, mbf);
  }
  writeout_kernel<<<256, 256, 0, stream>>>(memory, question, out);
}